// Round 1
// baseline (358.872 us; speedup 1.0000x reference)
//
#include <hip/hip_runtime.h>

// PeriodicRadiusGraph: out[i][j][s][c] = (cart[j] + shift_cart[s] - cart[i])[c]
// if dist2 < 25 and not (i==j && s==13), else 0.
// cart = frac @ cell (fp32), shift_cart = shifts({-1,0,1}^3, ij-order) @ cell.
// Output: 1024*1024*27*3 fp32 = ~340 MB -> store-bandwidth-bound (~54 us floor).

static constexpr int N    = 1024;
static constexpr int CPR  = 27 * N;     // cells per output row i (j*27+s)
static constexpr int HALF = CPR / 2;    // 13824 cells per block
static constexpr int TPB  = 256;
static constexpr int ITERS = HALF / TPB; // 54

__global__ __launch_bounds__(TPB, 8)
void prg_kernel(const float* __restrict__ frac,
                const float* __restrict__ cell,
                float* __restrict__ out) {
  __shared__ float4 cartL[N];    // 16 KB: cart positions, padded for b128 reads
  __shared__ float4 shiftL[27];  // 432 B: image translation vectors

  const int tid = threadIdx.x;
  const int i   = blockIdx.x >> 1;   // atom i (output row)
  const int h   = blockIdx.x & 1;    // which half of the row

  // cell matrix (uniform across block; 9 floats, L1-cached)
  const float c00 = cell[0], c01 = cell[1], c02 = cell[2];
  const float c10 = cell[3], c11 = cell[4], c12 = cell[5];
  const float c20 = cell[6], c21 = cell[7], c22 = cell[8];

  // cart = frac @ cell, ascending-k fma chain (match likely XLA dot order)
  for (int r = tid; r < N; r += TPB) {
    const float f0 = frac[3*r], f1 = frac[3*r+1], f2 = frac[3*r+2];
    float x = __fmul_rn(f0, c00); x = fmaf(f1, c10, x); x = fmaf(f2, c20, x);
    float y = __fmul_rn(f0, c01); y = fmaf(f1, c11, y); y = fmaf(f2, c21, y);
    float z = __fmul_rn(f0, c02); z = fmaf(f1, c12, z); z = fmaf(f2, c22, z);
    cartL[r] = make_float4(x, y, z, 0.0f);
  }
  if (tid < 27) {
    // shifts row r=(a,b,c): shift = (a-1, b-1, c-1); zero shift at r=13
    const float sx = (float)(tid / 9 - 1);
    const float sy = (float)((tid / 3) % 3 - 1);
    const float sz = (float)(tid % 3 - 1);
    float x = __fmul_rn(sx, c00); x = fmaf(sy, c10, x); x = fmaf(sz, c20, x);
    float y = __fmul_rn(sx, c01); y = fmaf(sy, c11, y); y = fmaf(sz, c21, y);
    float z = __fmul_rn(sx, c02); z = fmaf(sy, c12, z); z = fmaf(sz, c22, z);
    shiftL[tid] = make_float4(x, y, z, 0.0f);
  }
  __syncthreads();

  const float4 ci = cartL[i];   // LDS broadcast (uniform address)

  const int base = h * HALF + tid;
  float* orow = out + (size_t)i * (size_t)(CPR * 3);

  #pragma unroll 2
  for (int k = 0; k < ITERS; ++k) {
    const unsigned local = (unsigned)(base + k * TPB);  // j*27 + s
    const unsigned j = local / 27u;                     // magic-mul div
    const unsigned s = local - j * 27u;

    const float4 cj = cartL[j];   // ~3 distinct addrs/wave -> broadcast
    const float4 sh = shiftL[s];

    // disp = (cart_j + shift_s) - cart_i  (reference's evaluation order)
    const float d0 = __fsub_rn(__fadd_rn(cj.x, sh.x), ci.x);
    const float d1 = __fsub_rn(__fadd_rn(cj.y, sh.y), ci.y);
    const float d2 = __fsub_rn(__fadd_rn(cj.z, sh.z), ci.z);

    // dist2 = (d0^2 + d1^2) + d2^2, explicit no-contract rounding
    const float dist2 = __fadd_rn(
        __fadd_rn(__fmul_rn(d0, d0), __fmul_rn(d1, d1)), __fmul_rn(d2, d2));

    const bool ok = (dist2 < 25.0f) && !((j == (unsigned)i) && (s == 13u));

    float* p = orow + 3u * local;   // 12 B per cell, lanes contiguous
    p[0] = ok ? d0 : 0.0f;
    p[1] = ok ? d1 : 0.0f;
    p[2] = ok ? d2 : 0.0f;
  }
}

extern "C" void kernel_launch(void* const* d_in, const int* in_sizes, int n_in,
                              void* d_out, int out_size, void* d_ws, size_t ws_size,
                              hipStream_t stream) {
  const float* frac = (const float*)d_in[0];   // [1024,3] fp32
  const float* cell = (const float*)d_in[1];   // [3,3] fp32
  float* out = (float*)d_out;                  // [1024,1024,27,3] fp32
  prg_kernel<<<2 * N, TPB, 0, stream>>>(frac, cell, out);
}

// Round 2
// 343.143 us; speedup vs baseline: 1.0458x; 1.0458x over previous
//
#include <hip/hip_runtime.h>

// PeriodicRadiusGraph: out[i][j][s][c] = (cart[j] + shift_cart[s] - cart[i])[c]
// if dist2 < 25 and not (i==j && s==13), else 0.
// cart = frac @ cell, shift_cart = shifts({-1,0,1}^3, ij order) @ cell.
// Output 1024*1024*27*3 fp32 = ~340 MB -> pure store-BW-bound (~55 us floor at
// the 6.1 TB/s the harness's own fill kernel demonstrates).
//
// R2 change vs R1: fully-coalesced float4 stores. R1 stored 3 dwords/cell/lane
// (lane stride 12 B -> 3 partial-line store instrs, ~2.5 TB/s). Now lane L
// stores float4 at 16*L: each thread's 4 dwords span exactly 2 cells; compute
// both cells, select components by d0%3.

static constexpr int N    = 1024;
static constexpr int CPR  = 27 * N;          // cells per output row i
static constexpr int DWR  = CPR * 3;         // dwords per row = 82944
static constexpr int F4R  = DWR / 4;         // float4 per row = 20736
static constexpr int SEGS = 3;               // blocks per row
static constexpr int F4S  = F4R / SEGS;      // float4 per block = 6912
static constexpr int TPB  = 256;
static constexpr int ITERS = F4S / TPB;      // 27

__global__ __launch_bounds__(TPB, 8)
void prg_kernel(const float* __restrict__ frac,
                const float* __restrict__ cell,
                float* __restrict__ out) {
  __shared__ float4 cartL[N];    // 16 KB, float4-padded for b128 reads
  __shared__ float4 shiftL[27];

  const int tid = threadIdx.x;
  const unsigned bid = blockIdx.x;
  const unsigned i   = bid / SEGS;   // output row (atom i)
  const unsigned seg = bid % SEGS;   // third of the row

  // cell matrix (wave-uniform, L1-cached)
  const float c00 = cell[0], c01 = cell[1], c02 = cell[2];
  const float c10 = cell[3], c11 = cell[4], c12 = cell[5];
  const float c20 = cell[6], c21 = cell[7], c22 = cell[8];

  // cart = frac @ cell, ascending-k: mul then fma chain (matches R1, which passed)
  for (int r = tid; r < N; r += TPB) {
    const float f0 = frac[3*r], f1 = frac[3*r+1], f2 = frac[3*r+2];
    float x = __fmul_rn(f0, c00); x = fmaf(f1, c10, x); x = fmaf(f2, c20, x);
    float y = __fmul_rn(f0, c01); y = fmaf(f1, c11, y); y = fmaf(f2, c21, y);
    float z = __fmul_rn(f0, c02); z = fmaf(f1, c12, z); z = fmaf(f2, c22, z);
    cartL[r] = make_float4(x, y, z, 0.0f);
  }
  if (tid < 27) {
    const float sx = (float)(tid / 9 - 1);
    const float sy = (float)((tid / 3) % 3 - 1);
    const float sz = (float)(tid % 3 - 1);
    float x = __fmul_rn(sx, c00); x = fmaf(sy, c10, x); x = fmaf(sz, c20, x);
    float y = __fmul_rn(sx, c01); y = fmaf(sy, c11, y); y = fmaf(sz, c21, y);
    float z = __fmul_rn(sx, c02); z = fmaf(sy, c12, z); z = fmaf(sz, c22, z);
    shiftL[tid] = make_float4(x, y, z, 0.0f);
  }
  __syncthreads();

  const float4 ci = cartL[i];   // uniform address -> LDS broadcast

  float4* __restrict__ orow =
      reinterpret_cast<float4*>(out + (size_t)i * (size_t)DWR);

  unsigned g = seg * F4S + (unsigned)tid;   // float4 index within row

  #pragma unroll 3
  for (int k = 0; k < ITERS; ++k, g += TPB) {
    const unsigned d0 = 4u * g;          // first dword of this float4
    const unsigned c0 = d0 / 3u;         // first cell covered (magic-mul div)
    const unsigned r  = d0 - 3u * c0;    // offset of d0 within cell c0: 0..2
    const unsigned j0 = c0 / 27u;
    const unsigned s0 = c0 - 27u * j0;
    unsigned j1 = j0, s1 = s0 + 1u;      // second cell = c0 + 1
    if (s1 == 27u) { s1 = 0u; j1 = j0 + 1u; }

    const float4 cj0 = cartL[j0];
    const float4 sh0 = shiftL[s0];
    const float4 cj1 = cartL[j1];
    const float4 sh1 = shiftL[s1];

    // cell A: disp = (cart_j + shift_s) - cart_i   (reference eval order)
    float a0 = __fsub_rn(__fadd_rn(cj0.x, sh0.x), ci.x);
    float a1 = __fsub_rn(__fadd_rn(cj0.y, sh0.y), ci.y);
    float a2 = __fsub_rn(__fadd_rn(cj0.z, sh0.z), ci.z);
    const float da = __fadd_rn(
        __fadd_rn(__fmul_rn(a0, a0), __fmul_rn(a1, a1)), __fmul_rn(a2, a2));
    const bool oka = (da < 25.0f) && !((j0 == i) && (s0 == 13u));
    a0 = oka ? a0 : 0.0f; a1 = oka ? a1 : 0.0f; a2 = oka ? a2 : 0.0f;

    // cell B
    float b0 = __fsub_rn(__fadd_rn(cj1.x, sh1.x), ci.x);
    float b1 = __fsub_rn(__fadd_rn(cj1.y, sh1.y), ci.y);
    float b2 = __fsub_rn(__fadd_rn(cj1.z, sh1.z), ci.z);
    const float db = __fadd_rn(
        __fadd_rn(__fmul_rn(b0, b0), __fmul_rn(b1, b1)), __fmul_rn(b2, b2));
    const bool okb = (db < 25.0f) && !((j1 == i) && (s1 == 13u));
    b0 = okb ? b0 : 0.0f; b1 = okb ? b1 : 0.0f; b2 = okb ? b2 : 0.0f;

    // assemble float4 from the 6-dword window [a0 a1 a2 b0 b1 b2] at offset r
    const bool r0 = (r == 0u), r1 = (r == 1u);
    float4 w;
    w.x = r0 ? a0 : (r1 ? a1 : a2);
    w.y = r0 ? a1 : (r1 ? a2 : b0);
    w.z = r0 ? a2 : (r1 ? b0 : b1);
    w.w = r0 ? b0 : (r1 ? b1 : b2);

    orow[g] = w;   // lane-contiguous 16 B: 1 KB/wave store instruction
  }
}

extern "C" void kernel_launch(void* const* d_in, const int* in_sizes, int n_in,
                              void* d_out, int out_size, void* d_ws, size_t ws_size,
                              hipStream_t stream) {
  const float* frac = (const float*)d_in[0];   // [1024,3] fp32
  const float* cell = (const float*)d_in[1];   // [3,3] fp32
  float* out = (float*)d_out;                  // [1024,1024,27,3] fp32
  prg_kernel<<<N * SEGS, TPB, 0, stream>>>(frac, cell, out);
}

// Round 3
// 338.223 us; speedup vs baseline: 1.0611x; 1.0145x over previous
//
#include <hip/hip_runtime.h>

// PeriodicRadiusGraph: out[i][j][s][c] = (cart[j] + shift_cart[s] - cart[i])[c]
// if dist2 < 25 and not (i==j && s==13), else 0.  Output 340 MB fp32 ->
// store-BW-bound; harness fill proves ~6.1 TB/s achievable (~55 us floor).
//
// R3: period-81 tiling. Total threads NT = 81*2^13 = 663,552, so each thread's
// per-iteration dword stride (4*NT) is a multiple of 81*1024: j, s, r and the
// shift vectors are LOOP-INVARIANT per thread; only i advances (+32/iter).
// cart[j]+shift[s] is pre-added into registers; no LDS, no barrier; inner loop
// = 2 uniform L1 loads + ~40 VALU + 1 coalesced dwordx4 store.

static constexpr int N      = 1024;
static constexpr int TPB    = 256;
static constexpr int BLOCKS = 2592;                 // NT = 663,552 = 81 * 8192
static constexpr int ITERS  = 32;                   // 2592*256*32 f4 = whole tensor
static constexpr unsigned NT      = (unsigned)BLOCKS * TPB;
static constexpr unsigned DSTRIDE = 4u * NT;        // dwords per iter = 2,654,208
static constexpr unsigned ISTRIDE = 32u;            // i advance per iter (exact)

// ---- kernel 1: cart = frac @ cell and shift_cart into d_ws (L1-resident 16.4 KB)
__global__ __launch_bounds__(1024)
void prg_prep(const float* __restrict__ frac, const float* __restrict__ cell,
              float4* __restrict__ ws) {
  const int t = threadIdx.x;   // 1024 threads, 1 block
  const float c00 = cell[0], c01 = cell[1], c02 = cell[2];
  const float c10 = cell[3], c11 = cell[4], c12 = cell[5];
  const float c20 = cell[6], c21 = cell[7], c22 = cell[8];
  {
    const float f0 = frac[3*t], f1 = frac[3*t+1], f2 = frac[3*t+2];
    float x = __fmul_rn(f0,c00); x = fmaf(f1,c10,x); x = fmaf(f2,c20,x);
    float y = __fmul_rn(f0,c01); y = fmaf(f1,c11,y); y = fmaf(f2,c21,y);
    float z = __fmul_rn(f0,c02); z = fmaf(f1,c12,z); z = fmaf(f2,c22,z);
    ws[t] = make_float4(x,y,z,0.f);
  }
  if (t < 27) {
    const float sx = (float)(t/9 - 1), sy = (float)((t/3)%3 - 1), sz = (float)(t%3 - 1);
    float x = __fmul_rn(sx,c00); x = fmaf(sy,c10,x); x = fmaf(sz,c20,x);
    float y = __fmul_rn(sx,c01); y = fmaf(sy,c11,y); y = fmaf(sz,c21,y);
    float z = __fmul_rn(sx,c02); z = fmaf(sy,c12,z); z = fmaf(sz,c22,z);
    ws[N + t] = make_float4(x,y,z,0.f);
  }
}

// ---- kernel 2: the store stream
__global__ __launch_bounds__(TPB)
void prg_main(const float4* __restrict__ ws, float* __restrict__ out) {
  const unsigned T  = blockIdx.x * TPB + threadIdx.x;   // [0, 663552)
  const unsigned D0 = 4u * T;                           // first dword of my float4
  // decode (loop-invariant): cellA = D0/3, r = D0%3, then (i,j,s)
  const unsigned cellA = D0 / 3u;
  const unsigned r     = D0 - 3u*cellA;
  const unsigned c27A  = cellA / 27u;
  const unsigned sA    = cellA - 27u*c27A;
  const unsigned jA    = c27A & 1023u;
  unsigned       iA    = c27A >> 10;
  const bool wrapA     = (sA == 26u);
  const unsigned c27B  = c27A + (wrapA ? 1u : 0u);
  const unsigned sB    = wrapA ? 0u : (sA + 1u);
  const unsigned jB    = c27B & 1023u;
  unsigned       iB    = c27B >> 10;

  // loop-invariant operands: p = cart[j] + shift[s]  (reference's first add)
  const float4 cjA = ws[jA],     cjB = ws[jB];
  const float4 shA = ws[N + sA], shB = ws[N + sB];
  const float pAx = __fadd_rn(cjA.x, shA.x);
  const float pAy = __fadd_rn(cjA.y, shA.y);
  const float pAz = __fadd_rn(cjA.z, shA.z);
  const float pBx = __fadd_rn(cjB.x, shB.x);
  const float pBy = __fadd_rn(cjB.y, shB.y);
  const float pBz = __fadd_rn(cjB.z, shB.z);
  // self-edge only possible when s==13; fold s-check into an impossible j
  const unsigned jSelfA = (sA == 13u) ? jA : 0xFFFFFFFFu;
  const unsigned jSelfB = (sB == 13u) ? jB : 0xFFFFFFFFu;
  const bool r0 = (r == 0u), r1 = (r == 1u);

  float* outp = out + (size_t)D0;

  #pragma unroll 2
  for (int k = 0; k < ITERS; ++k) {
    const float4 ciA = ws[iA];   // wave-uniform address -> 1 L1 line
    const float4 ciB = ws[iB];

    float a0 = __fsub_rn(pAx, ciA.x);
    float a1 = __fsub_rn(pAy, ciA.y);
    float a2 = __fsub_rn(pAz, ciA.z);
    const float da = __fadd_rn(
        __fadd_rn(__fmul_rn(a0,a0), __fmul_rn(a1,a1)), __fmul_rn(a2,a2));
    const bool oka = (da < 25.0f) && (jSelfA != iA);
    a0 = oka ? a0 : 0.f; a1 = oka ? a1 : 0.f; a2 = oka ? a2 : 0.f;

    float b0 = __fsub_rn(pBx, ciB.x);
    float b1 = __fsub_rn(pBy, ciB.y);
    float b2 = __fsub_rn(pBz, ciB.z);
    const float db = __fadd_rn(
        __fadd_rn(__fmul_rn(b0,b0), __fmul_rn(b1,b1)), __fmul_rn(b2,b2));
    const bool okb = (db < 25.0f) && (jSelfB != iB);
    b0 = okb ? b0 : 0.f; b1 = okb ? b1 : 0.f; b2 = okb ? b2 : 0.f;

    // window [a0 a1 a2 b0 b1 b2] at loop-invariant offset r
    float4 w;
    w.x = r0 ? a0 : (r1 ? a1 : a2);
    w.y = r0 ? a1 : (r1 ? a2 : b0);
    w.z = r0 ? a2 : (r1 ? b0 : b1);
    w.w = r0 ? b0 : (r1 ? b1 : b2);

    *reinterpret_cast<float4*>(outp) = w;   // lane-contiguous 1 KB/wave
    outp += (size_t)DSTRIDE;
    iA += ISTRIDE; iB += ISTRIDE;
  }
}

extern "C" void kernel_launch(void* const* d_in, const int* in_sizes, int n_in,
                              void* d_out, int out_size, void* d_ws, size_t ws_size,
                              hipStream_t stream) {
  const float* frac = (const float*)d_in[0];   // [1024,3] fp32
  const float* cell = (const float*)d_in[1];   // [3,3] fp32
  float4* ws = (float4*)d_ws;                  // cart[1024] + shift[27]
  float* out = (float*)d_out;                  // [1024,1024,27,3] fp32
  prg_prep<<<1, 1024, 0, stream>>>(frac, cell, ws);
  prg_main<<<BLOCKS, TPB, 0, stream>>>(ws, out);
}